// Round 3
// baseline (3189.655 us; speedup 1.0000x reference)
//
#include <hip/hip_runtime.h>
#include <hip/hip_bf16.h>

using short8  = __attribute__((ext_vector_type(8))) short;
using floatx4 = __attribute__((ext_vector_type(4))) float;
typedef unsigned short u16;
typedef unsigned int   u32;

#define DEVINL static __device__ __forceinline__

constexpr int kB = 512;    // batch
constexpr int kH = 1024;   // hidden
constexpr int kO = 256;    // output dim
constexpr int kT = 128;    // timesteps
constexpr int kG = 4096;   // 4*H gate columns

DEVINL u16 f2bf(float x) {
  union { float f; unsigned u; } v; v.f = x;
  unsigned r = v.u + 0x7fffu + ((v.u >> 16) & 1u);   // RNE
  return (u16)(r >> 16);
}
DEVINL float sigm(float x)  { return 1.0f / (1.0f + __expf(-x)); }
DEVINL float tanhx(float x) { return 1.0f - 2.0f / (__expf(2.0f * x) + 1.0f); }

DEVINL void gload16(const void* src, void* ldsbase) {
  __builtin_amdgcn_global_load_lds((__attribute__((address_space(1))) void*)(char*)src,
                                   (__attribute__((address_space(3))) void*)ldsbase,
                                   16, 0, 0);
}
DEVINL short8 lds8(const void* p) { return *(const short8*)p; }

// ---------------- prep kernels ----------------

__global__ void k_init(const float* __restrict__ enc, float* __restrict__ c,
                       u16* __restrict__ h0) {
  int i = blockIdx.x * 256 + threadIdx.x;
  c[i]  = 0.0f;
  h0[i] = f2bf(enc[i]);
}

__global__ void k_zbar(u32* __restrict__ bar) {
  bar[threadIdx.x] = 0u;   // 512 counters (128 steps x 4 groups)
}

// bias0 = b_ih + b_hh ; bias1 = bias0 + W_ih @ b_out
__global__ void k_bias(const float* __restrict__ bih, const float* __restrict__ bhh,
                       const float* __restrict__ Wih, const float* __restrict__ bout,
                       float* __restrict__ bias0, float* __restrict__ bias1) {
  int n = blockIdx.x * 256 + threadIdx.x;        // 0..4095
  float b0 = bih[n] + bhh[n];
  const float* row = Wih + (long)n * 256;
  float s = 0.f;
  for (int j = 0; j < 256; ++j) s += row[j] * bout[j];
  bias0[n] = b0;
  bias1[n] = b0 + s;
}

// Wt0[r(n,g)][k] = bf16(W_hh[g*1024+n][k]);  r(n,g) = (n>>4)*64 + g*16 + (n&15)
__global__ void k_w0(const float* __restrict__ Whh, u16* __restrict__ Wt0) {
  const int r = blockIdx.x;                       // 4096 rows
  const int k = threadIdx.x * 4;
  const int n = ((r >> 6) << 4) | (r & 15);
  const int g = (r >> 4) & 3;
  const float4 v = *(const float4*)(Whh + (long)(g * 1024 + n) * 1024 + k);
  ushort4 o; o.x = f2bf(v.x); o.y = f2bf(v.y); o.z = f2bf(v.z); o.w = f2bf(v.w);
  *(ushort4*)(Wt0 + (long)r * 1024 + k) = o;
}

// Wob = bf16(W_out)
__global__ void k_wo(const float* __restrict__ Wout, u16* __restrict__ Wob) {
  const long i = ((long)blockIdx.x * 256 + threadIdx.x) * 4;
  const float4 v = *(const float4*)(Wout + i);
  ushort4 o; o.x = f2bf(v.x); o.y = f2bf(v.y); o.z = f2bf(v.z); o.w = f2bf(v.w);
  *(ushort4*)(Wob + i) = o;
}

// Wt1[r(n,g)][k] = bf16( W_hh[g*1024+n][k] + sum_j W_out[j][k]*W_ih[g*1024+n][j] )
__global__ __launch_bounds__(256) void k_w1(
    const float* __restrict__ Wih, const float* __restrict__ Wout,
    const float* __restrict__ Whh, u16* __restrict__ Wt1) {
  __shared__ float sW[16][256];
  const int g = blockIdx.x & 3, n16 = blockIdx.x >> 2;
  const int tid = threadIdx.x;
#pragma unroll
  for (int nl = 0; nl < 16; ++nl)
    sW[nl][tid] = Wih[(long)(g * 1024 + n16 * 16 + nl) * 256 + tid];
  __syncthreads();
  const int k4 = tid * 4;
  float acc[16][4];
#pragma unroll
  for (int nl = 0; nl < 16; ++nl)
#pragma unroll
    for (int q = 0; q < 4; ++q) acc[nl][q] = 0.f;
  for (int j = 0; j < 256; ++j) {
    const float4 wo = *(const float4*)(Wout + (long)j * 1024 + k4);
#pragma unroll
    for (int nl = 0; nl < 16; ++nl) {
      const float w = sW[nl][j];
      acc[nl][0] += w * wo.x; acc[nl][1] += w * wo.y;
      acc[nl][2] += w * wo.z; acc[nl][3] += w * wo.w;
    }
  }
#pragma unroll
  for (int nl = 0; nl < 16; ++nl) {
    const int n = n16 * 16 + nl;
    const int rout = n16 * 64 + g * 16 + nl;
    const float* hh = Whh + (long)(g * 1024 + n) * 1024 + k4;
    ushort4 o;
    o.x = f2bf(hh[0] + acc[nl][0]); o.y = f2bf(hh[1] + acc[nl][1]);
    o.z = f2bf(hh[2] + acc[nl][2]); o.w = f2bf(hh[3] + acc[nl][3]);
    *(ushort4*)(Wt1 + (long)rout * 1024 + k4) = o;
  }
}

// ---------------- step 0 (old-style, Wt0/bias0) ----------------
__global__ __launch_bounds__(256) void k_step(
    const u16* __restrict__ Xprev, u16* __restrict__ Hnext,
    float* __restrict__ c, const u16* __restrict__ Wt,
    const float* __restrict__ bias) {
  __shared__ u16 As[64 * 64];
  __shared__ u16 Bs[128 * 64];

  const int tid  = threadIdx.x;
  const int lane = tid & 63;
  const int wid  = tid >> 6;
  const int wr   = wid >> 1;
  const int wc   = wid & 1;
  const int n0   = blockIdx.x * 32;
  const int m0   = blockIdx.y * 64;
  const long wrow0 = (long)n0 * 4;
  const int hi  = lane >> 4;
  const int l15 = lane & 15;

  floatx4 acc[2][4];
#pragma unroll
  for (int a2 = 0; a2 < 2; ++a2)
#pragma unroll
    for (int f = 0; f < 4; ++f)
#pragma unroll
      for (int r = 0; r < 4; ++r) acc[a2][f][r] = 0.0f;

  for (int kt = 0; kt < 16; ++kt) {
    const int kb = kt * 128;
#pragma unroll
    for (int i = 0; i < 2; ++i) {
      const int u = i * 256 + tid;
      const int row = u >> 3;
      const int off = (u & 7) * 16;
      const char* src = (const char*)Xprev + ((long)(m0 + row) << 11) + kb +
                        (off ^ ((row & 7) << 4));
      gload16(src, (char*)As + (i * 256 + wid * 64) * 16);
    }
#pragma unroll
    for (int i = 0; i < 4; ++i) {
      const int u = i * 256 + tid;
      const int col = u >> 3;
      const int off = (u & 7) * 16;
      const char* src = (const char*)Wt + ((wrow0 + col) << 11) + kb +
                        (off ^ ((col & 7) << 4));
      gload16(src, (char*)Bs + (i * 256 + wid * 64) * 16);
    }
    __syncthreads();
#pragma unroll
    for (int ks = 0; ks < 2; ++ks) {
      const int kbyte = ks * 64 + hi * 16;
      const int ra = wr * 32 + l15;
      short8 a0 = lds8((const char*)As + ra * 128 + (kbyte ^ ((ra & 7) << 4)));
      const int rb = ra + 16;
      short8 a1 = lds8((const char*)As + rb * 128 + (kbyte ^ ((rb & 7) << 4)));
#pragma unroll
      for (int f = 0; f < 4; ++f) {
        const int colx = wc * 64 + f * 16 + l15;
        short8 b = lds8((const char*)Bs + colx * 128 + (kbyte ^ ((colx & 7) << 4)));
        acc[0][f] = __builtin_amdgcn_mfma_f32_16x16x32_bf16(a0, b, acc[0][f], 0, 0, 0);
        acc[1][f] = __builtin_amdgcn_mfma_f32_16x16x32_bf16(a1, b, acc[1][f], 0, 0, 0);
      }
    }
    __syncthreads();
  }

  const int n_glob = n0 + wc * 16 + l15;
  const float bi = bias[n_glob];
  const float bf = bias[1024 + n_glob];
  const float bg = bias[2048 + n_glob];
  const float bo = bias[3072 + n_glob];
#pragma unroll
  for (int a2 = 0; a2 < 2; ++a2) {
#pragma unroll
    for (int r = 0; r < 4; ++r) {
      const int row = m0 + wr * 32 + a2 * 16 + hi * 4 + r;
      const long ci = (long)row * kH + n_glob;
      const float iv = sigm(acc[a2][0][r] + bi);
      const float fv = sigm(acc[a2][1][r] + bf);
      const float gv = tanhx(acc[a2][2][r] + bg);
      const float ov = sigm(acc[a2][3][r] + bo);
      const float cn = fv * c[ci] + iv * gv;
      c[ci] = cn;
      Hnext[ci] = f2bf(ov * tanhx(cn));
    }
  }
}

// ---------------- persistent recurrence: steps 1..127 ----------------
// 256 blocks (1/CU, co-resident: 128KB LDS), 8 waves. Block (bg,hg):
// batch rows bg*128.. , Wt1 rows hg*64..hg*64+63 (16 hidden x 4 gates),
// weights LDS-resident (XOR-swizzled), c in registers, A read from global.
__global__ __launch_bounds__(512, 2) void k_persist(
    const u16* __restrict__ Wt,      // Wt1 [4096][1024]
    const float* __restrict__ bias,  // bias1
    const float* __restrict__ cin,   // c after step 0
    u16* __restrict__ Hbuf,          // 129 slices of [512][1024]
    u32* __restrict__ bar) {
  __shared__ u16 Wlds[64 * 1024];    // 128 KB

  const int tid = threadIdx.x;
  const int l   = tid & 63;
  const int w   = tid >> 6;          // wave 0..7 -> rows w*16..
  const int l15 = l & 15;
  const int hi  = l >> 4;
  const int hg  = blockIdx.x & 63;
  const int bg  = blockIdx.x >> 6;
  const int m0  = bg * 128;

  // stage weight slice once: linear LDS dest, inverse-swizzled global src
  {
    const long wrow0 = (long)hg * 64;
#pragma unroll
    for (int rr = 0; rr < 16; ++rr) {
      const int u = rr * 512 + tid;            // 16B chunk id 0..8191
      const int col   = u >> 7;                // 0..63
      const int kphys = u & 127;
      const int klog  = kphys ^ (col & 7);
      const char* src = (const char*)Wt + ((wrow0 + col) << 11) + klog * 16;
      gload16(src, (char*)Wlds + (long)u * 16);
    }
  }

  const int ncol = hg * 16 + l15;              // hidden column owned
  const float bi = bias[ncol];
  const float bf_ = bias[1024 + ncol];
  const float bg_ = bias[2048 + ncol];
  const float bo = bias[3072 + ncol];
  const int row0 = m0 + w * 16 + hi * 4;
  float creg[4];
#pragma unroll
  for (int r = 0; r < 4; ++r) creg[r] = cin[(long)(row0 + r) * kH + ncol];

  // B ds_read: physical byte = (col<<11) + ((hi^s01)<<4) + (((j^s2))<<6)
  // (s2 flips only bit0 of j -> exact XOR fold; NO s2 term in the base!)
  const int s01 = l15 & 3, s2 = (l15 >> 2) & 1;
  int baseBx[4];
#pragma unroll
  for (int f = 0; f < 4; ++f)
    baseBx[f] = ((f * 16 + l15) << 11) + ((hi ^ s01) << 4);

  __syncthreads();                             // weights staged (vmcnt drained)

  const long arow = (long)(m0 + w * 16 + l15) * 2048 + hi * 16;  // A byte offset
  const long HSB  = (long)kB * kH * 2;                            // slice bytes

  for (int t = 1; t < kT; ++t) {
    const char* Asrc = (const char*)Hbuf + (long)t * HSB + arow;
    floatx4 ac0 = {0.f,0.f,0.f,0.f}, ac1 = ac0, ac2 = ac0, ac3 = ac0;

    short8 a0 = *(const short8*)(Asrc + 0 * 64);
    short8 a1 = *(const short8*)(Asrc + 1 * 64);
    short8 a2 = *(const short8*)(Asrc + 2 * 64);
    short8 a3 = *(const short8*)(Asrc + 3 * 64);
#pragma unroll
    for (int jg = 0; jg < 8; ++jg) {
      short8 n0v, n1v, n2v, n3v;
      if (jg < 7) {
        n0v = *(const short8*)(Asrc + (jg * 4 + 4) * 64);
        n1v = *(const short8*)(Asrc + (jg * 4 + 5) * 64);
        n2v = *(const short8*)(Asrc + (jg * 4 + 6) * 64);
        n3v = *(const short8*)(Asrc + (jg * 4 + 7) * 64);
      }
#pragma unroll
      for (int q = 0; q < 4; ++q) {
        const int joff = ((jg * 4 + (q ^ s2)) << 6);   // (j ^ s2) << 6
        short8 av = (q == 0) ? a0 : (q == 1) ? a1 : (q == 2) ? a2 : a3;
        short8 b0 = lds8((const char*)Wlds + baseBx[0] + joff);
        short8 b1 = lds8((const char*)Wlds + baseBx[1] + joff);
        short8 b2 = lds8((const char*)Wlds + baseBx[2] + joff);
        short8 b3 = lds8((const char*)Wlds + baseBx[3] + joff);
        ac0 = __builtin_amdgcn_mfma_f32_16x16x32_bf16(av, b0, ac0, 0, 0, 0);
        ac1 = __builtin_amdgcn_mfma_f32_16x16x32_bf16(av, b1, ac1, 0, 0, 0);
        ac2 = __builtin_amdgcn_mfma_f32_16x16x32_bf16(av, b2, ac2, 0, 0, 0);
        ac3 = __builtin_amdgcn_mfma_f32_16x16x32_bf16(av, b3, ac3, 0, 0, 0);
      }
      a0 = n0v; a1 = n1v; a2 = n2v; a3 = n3v;
    }

    // cell update + h write
    u16* Hn = (u16*)((char*)Hbuf + (long)(t + 1) * HSB);
#pragma unroll
    for (int r = 0; r < 4; ++r) {
      const float iv = sigm(ac0[r] + bi);
      const float fv = sigm(ac1[r] + bf_);
      const float gv = tanhx(ac2[r] + bg_);
      const float ov = sigm(ac3[r] + bo);
      const float cn = fv * creg[r] + iv * gv;
      creg[r] = cn;
      Hn[(long)(row0 + r) * kH + ncol] = f2bf(ov * tanhx(cn));
    }

    if (t < kT - 1) {
      __syncthreads();                         // drain h stores (vmcnt0)
      if (tid == 0) {
        u32* p = bar + (t * 4 + bg);
        __hip_atomic_fetch_add(p, 1u, __ATOMIC_RELEASE, __HIP_MEMORY_SCOPE_AGENT);
        int guard = 0;
        while (__hip_atomic_load(p, __ATOMIC_RELAXED, __HIP_MEMORY_SCOPE_AGENT) < 64u) {
          __builtin_amdgcn_s_sleep(4);
          if (++guard > (1 << 16)) break;      // fail visibly, never hang
        }
        __threadfence();                       // agent acquire (inv L1/L2)
      }
      __syncthreads();
    }
  }
}

// ---------------- prediction head ----------------
__global__ __launch_bounds__(256) void k_pred(
    const u16* __restrict__ Hbuf, long HS, int nsl,
    const u16* __restrict__ Wob, const float* __restrict__ b_out,
    float* __restrict__ out, int t0) {
  __shared__ u16 As[64 * 64];
  __shared__ u16 Bs[128 * 64];
  const int t = t0 + blockIdx.z;
  const u16* Hm = Hbuf + (long)((t + 1) % nsl) * HS;

  const int tid = threadIdx.x, lane = tid & 63, wid = tid >> 6;
  const int wr = wid >> 1, wc = wid & 1;
  const int m0 = blockIdx.y * 64;
  const int o0 = blockIdx.x * 128;
  const int hi = lane >> 4, l15 = lane & 15;

  floatx4 acc[2][4];
#pragma unroll
  for (int a2 = 0; a2 < 2; ++a2)
#pragma unroll
    for (int f = 0; f < 4; ++f)
#pragma unroll
      for (int r = 0; r < 4; ++r) acc[a2][f][r] = 0.0f;

  for (int kt = 0; kt < 16; ++kt) {
    const int kb = kt * 128;
#pragma unroll
    for (int i = 0; i < 2; ++i) {
      const int u = i * 256 + tid;
      const int row = u >> 3;
      const int off = (u & 7) * 16;
      const char* src = (const char*)Hm + ((long)(m0 + row) << 11) + kb +
                        (off ^ ((row & 7) << 4));
      gload16(src, (char*)As + (i * 256 + wid * 64) * 16);
    }
#pragma unroll
    for (int i = 0; i < 4; ++i) {
      const int u = i * 256 + tid;
      const int col = u >> 3;
      const int off = (u & 7) * 16;
      const char* src = (const char*)Wob + ((long)(o0 + col) << 11) + kb +
                        (off ^ ((col & 7) << 4));
      gload16(src, (char*)Bs + (i * 256 + wid * 64) * 16);
    }
    __syncthreads();
#pragma unroll
    for (int ks = 0; ks < 2; ++ks) {
      const int kbyte = ks * 64 + hi * 16;
      const int ra = wr * 32 + l15;
      short8 a0 = lds8((const char*)As + ra * 128 + (kbyte ^ ((ra & 7) << 4)));
      const int rb = ra + 16;
      short8 a1 = lds8((const char*)As + rb * 128 + (kbyte ^ ((rb & 7) << 4)));
#pragma unroll
      for (int f = 0; f < 4; ++f) {
        const int colx = wc * 64 + f * 16 + l15;
        short8 b = lds8((const char*)Bs + colx * 128 + (kbyte ^ ((colx & 7) << 4)));
        acc[0][f] = __builtin_amdgcn_mfma_f32_16x16x32_bf16(a0, b, acc[0][f], 0, 0, 0);
        acc[1][f] = __builtin_amdgcn_mfma_f32_16x16x32_bf16(a1, b, acc[1][f], 0, 0, 0);
      }
    }
    __syncthreads();
  }

#pragma unroll
  for (int f = 0; f < 4; ++f) {
    const int o = o0 + wc * 64 + f * 16 + l15;
    const float bb = b_out[o];
#pragma unroll
    for (int a2 = 0; a2 < 2; ++a2)
#pragma unroll
      for (int r = 0; r < 4; ++r) {
        const int row = m0 + wr * 32 + a2 * 16 + hi * 4 + r;
        out[((long)row * kT + t) * kO + o] = acc[a2][f][r] + bb;
      }
  }
}

// ---------------- launcher ----------------
extern "C" void kernel_launch(void* const* d_in, const int* in_sizes, int n_in,
                              void* d_out, int out_size, void* d_ws, size_t ws_size,
                              hipStream_t stream) {
  const float* enc  = (const float*)d_in[0];
  const float* Wih  = (const float*)d_in[2];
  const float* Whh  = (const float*)d_in[3];
  const float* bih  = (const float*)d_in[4];
  const float* bhh  = (const float*)d_in[5];
  const float* Wout = (const float*)d_in[6];
  const float* bout = (const float*)d_in[7];
  float* out = (float*)d_out;
  char*  ws  = (char*)d_ws;

  size_t off = 0;
  auto take = [&](size_t bytes) {
    size_t o = off; off += (bytes + 255) & ~(size_t)255; return o;
  };
  u16*   Wt0   = (u16*)(ws + take((size_t)kG * kH * 2));   // 8 MB
  u16*   Wt1   = (u16*)(ws + take((size_t)kG * kH * 2));   // 8 MB
  u16*   Wob   = (u16*)(ws + take((size_t)kO * kH * 2));   // 0.5 MB
  float* bias0 = (float*)(ws + take((size_t)kG * 4));
  float* bias1 = (float*)(ws + take((size_t)kG * 4));
  float* cst   = (float*)(ws + take((size_t)kB * kH * 4)); // 2 MB
  u32*   bar   = (u32*)(ws + take(512 * 4));               // 2 KB
  const long HS = (long)kB * kH;
  u16* Hbuf = (u16*)(ws + off);
  const size_t havail = ws_size > off ? ws_size - off : 0;
  const bool fullhist = havail >= (size_t)(kT + 1) * HS * 2;
  const int nsl = fullhist ? (kT + 1) : 2;

  k_init<<<dim3(kB * kH / 256), dim3(256), 0, stream>>>(enc, cst, Hbuf);
  k_zbar<<<dim3(1), dim3(512), 0, stream>>>(bar);
  k_bias<<<dim3(kG / 256), dim3(256), 0, stream>>>(bih, bhh, Wih, bout, bias0, bias1);
  k_w0<<<dim3(kG), dim3(256), 0, stream>>>(Whh, Wt0);
  k_wo<<<dim3(kO * kH / 1024), dim3(256), 0, stream>>>(Wout, Wob);
  k_w1<<<dim3(256), dim3(256), 0, stream>>>(Wih, Wout, Whh, Wt1);

  if (fullhist) {
    // step 0 (Wt0/bias0), then persistent steps 1..127, then batched pred
    k_step<<<dim3(kH / 32, kB / 64), dim3(256), 0, stream>>>(
        Hbuf, Hbuf + HS, cst, Wt0, bias0);
    k_persist<<<dim3(256), dim3(512), 0, stream>>>(Wt1, bias1, cst, Hbuf, bar);
    k_pred<<<dim3(kO / 128, kB / 64, kT), dim3(256), 0, stream>>>(
        Hbuf, HS, nsl, Wob, bout, out, 0);
  } else {
    for (int t = 0; t < kT; ++t) {
      const u16* Xp = Hbuf + (long)(t % nsl) * HS;
      u16*       Hn = Hbuf + (long)((t + 1) % nsl) * HS;
      k_step<<<dim3(kH / 32, kB / 64), dim3(256), 0, stream>>>(
          Xp, Hn, cst, t == 0 ? Wt0 : Wt1, t == 0 ? bias0 : bias1);
      k_pred<<<dim3(kO / 128, kB / 64, 1), dim3(256), 0, stream>>>(
          Hbuf, HS, nsl, Wob, bout, out, t);
    }
  }
}

// Round 4
// 1989.203 us; speedup vs baseline: 1.6035x; 1.6035x over previous
//
#include <hip/hip_runtime.h>
#include <hip/hip_bf16.h>

using short8  = __attribute__((ext_vector_type(8))) short;
using floatx4 = __attribute__((ext_vector_type(4))) float;
typedef unsigned short u16;
typedef unsigned int   u32;

#define DEVINL static __device__ __forceinline__

constexpr int kB = 512;    // batch
constexpr int kH = 1024;   // hidden
constexpr int kO = 256;    // output dim
constexpr int kT = 128;    // timesteps
constexpr int kG = 4096;   // 4*H gate columns

DEVINL u16 f2bf(float x) {
  union { float f; unsigned u; } v; v.f = x;
  unsigned r = v.u + 0x7fffu + ((v.u >> 16) & 1u);   // RNE
  return (u16)(r >> 16);
}
DEVINL float sigm(float x)  { return 1.0f / (1.0f + __expf(-x)); }
DEVINL float tanhx(float x) { return 1.0f - 2.0f / (__expf(2.0f * x) + 1.0f); }

DEVINL void gload16(const void* src, void* ldsbase) {
  __builtin_amdgcn_global_load_lds((__attribute__((address_space(1))) void*)(char*)src,
                                   (__attribute__((address_space(3))) void*)ldsbase,
                                   16, 0, 0);
}
DEVINL short8 lds8(const void* p) { return *(const short8*)p; }

// ---------------- prep kernels ----------------

__global__ void k_init(const float* __restrict__ enc, float* __restrict__ c,
                       u16* __restrict__ h0) {
  int i = blockIdx.x * 256 + threadIdx.x;
  c[i]  = 0.0f;
  h0[i] = f2bf(enc[i]);
}

__global__ void k_zbar(u32* __restrict__ bar) {
  bar[threadIdx.x] = 0u;   // 512 counters (128 steps x 4 groups)
}

// bias0 = b_ih + b_hh ; bias1 = bias0 + W_ih @ b_out
__global__ void k_bias(const float* __restrict__ bih, const float* __restrict__ bhh,
                       const float* __restrict__ Wih, const float* __restrict__ bout,
                       float* __restrict__ bias0, float* __restrict__ bias1) {
  int n = blockIdx.x * 256 + threadIdx.x;        // 0..4095
  float b0 = bih[n] + bhh[n];
  const float* row = Wih + (long)n * 256;
  float s = 0.f;
  for (int j = 0; j < 256; ++j) s += row[j] * bout[j];
  bias0[n] = b0;
  bias1[n] = b0 + s;
}

// Wt0[r(n,g)][k] = bf16(W_hh[g*1024+n][k]);  r(n,g) = (n>>4)*64 + g*16 + (n&15)
__global__ void k_w0(const float* __restrict__ Whh, u16* __restrict__ Wt0) {
  const int r = blockIdx.x;                       // 4096 rows
  const int k = threadIdx.x * 4;
  const int n = ((r >> 6) << 4) | (r & 15);
  const int g = (r >> 4) & 3;
  const float4 v = *(const float4*)(Whh + (long)(g * 1024 + n) * 1024 + k);
  ushort4 o; o.x = f2bf(v.x); o.y = f2bf(v.y); o.z = f2bf(v.z); o.w = f2bf(v.w);
  *(ushort4*)(Wt0 + (long)r * 1024 + k) = o;
}

// Wob = bf16(W_out)
__global__ void k_wo(const float* __restrict__ Wout, u16* __restrict__ Wob) {
  const long i = ((long)blockIdx.x * 256 + threadIdx.x) * 4;
  const float4 v = *(const float4*)(Wout + i);
  ushort4 o; o.x = f2bf(v.x); o.y = f2bf(v.y); o.z = f2bf(v.z); o.w = f2bf(v.w);
  *(ushort4*)(Wob + i) = o;
}

// Wt1[r(n,g)][k] = bf16( W_hh[g*1024+n][k] + sum_j W_out[j][k]*W_ih[g*1024+n][j] )
__global__ __launch_bounds__(256) void k_w1(
    const float* __restrict__ Wih, const float* __restrict__ Wout,
    const float* __restrict__ Whh, u16* __restrict__ Wt1) {
  __shared__ float sW[16][256];
  const int g = blockIdx.x & 3, n16 = blockIdx.x >> 2;
  const int tid = threadIdx.x;
#pragma unroll
  for (int nl = 0; nl < 16; ++nl)
    sW[nl][tid] = Wih[(long)(g * 1024 + n16 * 16 + nl) * 256 + tid];
  __syncthreads();
  const int k4 = tid * 4;
  float acc[16][4];
#pragma unroll
  for (int nl = 0; nl < 16; ++nl)
#pragma unroll
    for (int q = 0; q < 4; ++q) acc[nl][q] = 0.f;
  for (int j = 0; j < 256; ++j) {
    const float4 wo = *(const float4*)(Wout + (long)j * 1024 + k4);
#pragma unroll
    for (int nl = 0; nl < 16; ++nl) {
      const float w = sW[nl][j];
      acc[nl][0] += w * wo.x; acc[nl][1] += w * wo.y;
      acc[nl][2] += w * wo.z; acc[nl][3] += w * wo.w;
    }
  }
#pragma unroll
  for (int nl = 0; nl < 16; ++nl) {
    const int n = n16 * 16 + nl;
    const int rout = n16 * 64 + g * 16 + nl;
    const float* hh = Whh + (long)(g * 1024 + n) * 1024 + k4;
    ushort4 o;
    o.x = f2bf(hh[0] + acc[nl][0]); o.y = f2bf(hh[1] + acc[nl][1]);
    o.z = f2bf(hh[2] + acc[nl][2]); o.w = f2bf(hh[3] + acc[nl][3]);
    *(ushort4*)(Wt1 + (long)rout * 1024 + k4) = o;
  }
}

// ---------------- step 0 (old-style, Wt0/bias0) ----------------
__global__ __launch_bounds__(256) void k_step(
    const u16* __restrict__ Xprev, u16* __restrict__ Hnext,
    float* __restrict__ c, const u16* __restrict__ Wt,
    const float* __restrict__ bias) {
  __shared__ u16 As[64 * 64];
  __shared__ u16 Bs[128 * 64];

  const int tid  = threadIdx.x;
  const int lane = tid & 63;
  const int wid  = tid >> 6;
  const int wr   = wid >> 1;
  const int wc   = wid & 1;
  const int n0   = blockIdx.x * 32;
  const int m0   = blockIdx.y * 64;
  const long wrow0 = (long)n0 * 4;
  const int hi  = lane >> 4;
  const int l15 = lane & 15;

  floatx4 acc[2][4];
#pragma unroll
  for (int a2 = 0; a2 < 2; ++a2)
#pragma unroll
    for (int f = 0; f < 4; ++f)
#pragma unroll
      for (int r = 0; r < 4; ++r) acc[a2][f][r] = 0.0f;

  for (int kt = 0; kt < 16; ++kt) {
    const int kb = kt * 128;
#pragma unroll
    for (int i = 0; i < 2; ++i) {
      const int u = i * 256 + tid;
      const int row = u >> 3;
      const int off = (u & 7) * 16;
      const char* src = (const char*)Xprev + ((long)(m0 + row) << 11) + kb +
                        (off ^ ((row & 7) << 4));
      gload16(src, (char*)As + (i * 256 + wid * 64) * 16);
    }
#pragma unroll
    for (int i = 0; i < 4; ++i) {
      const int u = i * 256 + tid;
      const int col = u >> 3;
      const int off = (u & 7) * 16;
      const char* src = (const char*)Wt + ((wrow0 + col) << 11) + kb +
                        (off ^ ((col & 7) << 4));
      gload16(src, (char*)Bs + (i * 256 + wid * 64) * 16);
    }
    __syncthreads();
#pragma unroll
    for (int ks = 0; ks < 2; ++ks) {
      const int kbyte = ks * 64 + hi * 16;
      const int ra = wr * 32 + l15;
      short8 a0 = lds8((const char*)As + ra * 128 + (kbyte ^ ((ra & 7) << 4)));
      const int rb = ra + 16;
      short8 a1 = lds8((const char*)As + rb * 128 + (kbyte ^ ((rb & 7) << 4)));
#pragma unroll
      for (int f = 0; f < 4; ++f) {
        const int colx = wc * 64 + f * 16 + l15;
        short8 b = lds8((const char*)Bs + colx * 128 + (kbyte ^ ((colx & 7) << 4)));
        acc[0][f] = __builtin_amdgcn_mfma_f32_16x16x32_bf16(a0, b, acc[0][f], 0, 0, 0);
        acc[1][f] = __builtin_amdgcn_mfma_f32_16x16x32_bf16(a1, b, acc[1][f], 0, 0, 0);
      }
    }
    __syncthreads();
  }

  const int n_glob = n0 + wc * 16 + l15;
  const float bi = bias[n_glob];
  const float bf = bias[1024 + n_glob];
  const float bg = bias[2048 + n_glob];
  const float bo = bias[3072 + n_glob];
#pragma unroll
  for (int a2 = 0; a2 < 2; ++a2) {
#pragma unroll
    for (int r = 0; r < 4; ++r) {
      const int row = m0 + wr * 32 + a2 * 16 + hi * 4 + r;
      const long ci = (long)row * kH + n_glob;
      const float iv = sigm(acc[a2][0][r] + bi);
      const float fv = sigm(acc[a2][1][r] + bf);
      const float gv = tanhx(acc[a2][2][r] + bg);
      const float ov = sigm(acc[a2][3][r] + bo);
      const float cn = fv * c[ci] + iv * gv;
      c[ci] = cn;
      Hnext[ci] = f2bf(ov * tanhx(cn));
    }
  }
}

// ---------------- persistent recurrence: steps 1..127 ----------------
// 256 blocks (1/CU, 128KB LDS), 8 waves. XCD-pair-clustered remap:
//   xcd = blk&7, slot = blk>>3; bg = xcd>>1; hg = (xcd&1)*32 + slot.
// -> each bg group lives on one XCD pair; every 128B h-line is produced
//    entirely within one XCD (no partial-line cross-XCD merge on read path).
// Weights LDS-resident, laid out EXACTLY in read order (conflict-free):
//   frag(f,j) bytes = (j*4+f)*1024 + lane*16.
__global__ __launch_bounds__(512, 2) void k_persist(
    const u16* __restrict__ Wt,      // Wt1 [4096][1024]
    const float* __restrict__ bias,  // bias1
    const float* __restrict__ cin,   // c after step 0
    u16* __restrict__ Hbuf,          // 129 slices of [512][1024]
    u32* __restrict__ bar) {
  __shared__ u16 Wlds[64 * 1024];    // 128 KB

  const int tid = threadIdx.x;
  const int l   = tid & 63;
  const int w   = tid >> 6;          // wave 0..7 -> rows w*16..
  const int l15 = l & 15;
  const int hi  = l >> 4;
  const int xcd  = blockIdx.x & 7;
  const int slot = blockIdx.x >> 3;            // 0..31
  const int bg   = xcd >> 1;                   // 0..3
  const int hg   = (xcd & 1) * 32 + slot;      // 0..63
  const int m0   = bg * 128;

  // stage weight slice once, in read-order layout:
  // LDS chunk u (16B) = (j*4+f)*64 + hi2*16 + c15  -> holds
  // Wt[hg*64 + f*16 + c15][bytes j*64 + hi2*16 .. +16]
  {
    const long wrow0 = (long)hg * 64;
#pragma unroll
    for (int rr = 0; rr < 16; ++rr) {
      const int u   = rr * 512 + tid;          // 0..8191
      const int j   = u >> 8;
      const int f   = (u >> 6) & 3;
      const int h2  = (u >> 4) & 3;
      const int c15 = u & 15;
      const char* src = (const char*)Wt + ((wrow0 + f * 16 + c15) << 11) +
                        (j << 6) + (h2 << 4);
      gload16(src, (char*)Wlds + (long)u * 16);
    }
  }

  const int ncol = hg * 16 + l15;              // hidden column owned
  const float bi = bias[ncol];
  const float bf_ = bias[1024 + ncol];
  const float bg_ = bias[2048 + ncol];
  const float bo = bias[3072 + ncol];
  const int row0 = m0 + w * 16 + hi * 4;
  float creg[4];
#pragma unroll
  for (int r = 0; r < 4; ++r) creg[r] = cin[(long)(row0 + r) * kH + ncol];

  __syncthreads();                             // weights staged (vmcnt drained)

  const char* wb = (const char*)Wlds + (l << 4);                  // lane base
  const long arow = (long)(m0 + w * 16 + l15) * 2048 + hi * 16;   // A byte off
  const long HSB  = (long)kB * kH * 2;                            // slice bytes

  for (int t = 1; t < kT; ++t) {
    const char* Asrc = (const char*)Hbuf + (long)t * HSB + arow;
    floatx4 ac0 = {0.f,0.f,0.f,0.f}, ac1 = ac0, ac2 = ac0, ac3 = ac0;

    short8 a0 = *(const short8*)(Asrc + 0 * 64);
    short8 a1 = *(const short8*)(Asrc + 1 * 64);
    short8 a2 = *(const short8*)(Asrc + 2 * 64);
    short8 a3 = *(const short8*)(Asrc + 3 * 64);
#pragma unroll
    for (int jg = 0; jg < 8; ++jg) {
      short8 n0v, n1v, n2v, n3v;
      if (jg < 7) {
        n0v = *(const short8*)(Asrc + (jg * 4 + 4) * 64);
        n1v = *(const short8*)(Asrc + (jg * 4 + 5) * 64);
        n2v = *(const short8*)(Asrc + (jg * 4 + 6) * 64);
        n3v = *(const short8*)(Asrc + (jg * 4 + 7) * 64);
      }
#pragma unroll
      for (int q = 0; q < 4; ++q) {
        const int j = jg * 4 + q;
        short8 av = (q == 0) ? a0 : (q == 1) ? a1 : (q == 2) ? a2 : a3;
        short8 b0 = lds8(wb + (j << 12) + 0 * 1024);
        short8 b1 = lds8(wb + (j << 12) + 1 * 1024);
        short8 b2 = lds8(wb + (j << 12) + 2 * 1024);
        short8 b3 = lds8(wb + (j << 12) + 3 * 1024);
        ac0 = __builtin_amdgcn_mfma_f32_16x16x32_bf16(av, b0, ac0, 0, 0, 0);
        ac1 = __builtin_amdgcn_mfma_f32_16x16x32_bf16(av, b1, ac1, 0, 0, 0);
        ac2 = __builtin_amdgcn_mfma_f32_16x16x32_bf16(av, b2, ac2, 0, 0, 0);
        ac3 = __builtin_amdgcn_mfma_f32_16x16x32_bf16(av, b3, ac3, 0, 0, 0);
      }
      a0 = n0v; a1 = n1v; a2 = n2v; a3 = n3v;
    }

    // cell update + h write
    u16* Hn = (u16*)((char*)Hbuf + (long)(t + 1) * HSB);
#pragma unroll
    for (int r = 0; r < 4; ++r) {
      const float iv = sigm(ac0[r] + bi);
      const float fv = sigm(ac1[r] + bf_);
      const float gv = tanhx(ac2[r] + bg_);
      const float ov = sigm(ac3[r] + bo);
      const float cn = fv * creg[r] + iv * gv;
      creg[r] = cn;
      Hn[(long)(row0 + r) * kH + ncol] = f2bf(ov * tanhx(cn));
    }

    if (t < kT - 1) {
      __syncthreads();                         // all waves' stores vmcnt-drained
      if (tid == 0) {
        u32* p = bar + (t * 4 + bg);
        // RELEASE at agent scope: wbL2 (flush this XCD's dirty h) + add at L3.
        __hip_atomic_fetch_add(p, 1u, __ATOMIC_RELEASE, __HIP_MEMORY_SCOPE_AGENT);
        int guard = 0;
        while (__hip_atomic_load(p, __ATOMIC_RELAXED, __HIP_MEMORY_SCOPE_AGENT) < 64u) {
          __builtin_amdgcn_s_sleep(1);
          if (++guard > (1 << 17)) break;      // fail visibly, never hang
        }
        // NO __threadfence(): consumer L2 holds no stale Hbuf[t+1] lines
        // (slices are write-once/read-once; co-XCD lines are fresh dirty hits,
        //  cross-XCD lines were never cached here -> miss to L3 post-wbl2).
      }
      __syncthreads();
    }
  }
}

// ---------------- prediction head ----------------
__global__ __launch_bounds__(256) void k_pred(
    const u16* __restrict__ Hbuf, long HS, int nsl,
    const u16* __restrict__ Wob, const float* __restrict__ b_out,
    float* __restrict__ out, int t0) {
  __shared__ u16 As[64 * 64];
  __shared__ u16 Bs[128 * 64];
  const int t = t0 + blockIdx.z;
  const u16* Hm = Hbuf + (long)((t + 1) % nsl) * HS;

  const int tid = threadIdx.x, lane = tid & 63, wid = tid >> 6;
  const int wr = wid >> 1, wc = wid & 1;
  const int m0 = blockIdx.y * 64;
  const int o0 = blockIdx.x * 128;
  const int hi = lane >> 4, l15 = lane & 15;

  floatx4 acc[2][4];
#pragma unroll
  for (int a2 = 0; a2 < 2; ++a2)
#pragma unroll
    for (int f = 0; f < 4; ++f)
#pragma unroll
      for (int r = 0; r < 4; ++r) acc[a2][f][r] = 0.0f;

  for (int kt = 0; kt < 16; ++kt) {
    const int kb = kt * 128;
#pragma unroll
    for (int i = 0; i < 2; ++i) {
      const int u = i * 256 + tid;
      const int row = u >> 3;
      const int off = (u & 7) * 16;
      const char* src = (const char*)Hm + ((long)(m0 + row) << 11) + kb +
                        (off ^ ((row & 7) << 4));
      gload16(src, (char*)As + (i * 256 + wid * 64) * 16);
    }
#pragma unroll
    for (int i = 0; i < 4; ++i) {
      const int u = i * 256 + tid;
      const int col = u >> 3;
      const int off = (u & 7) * 16;
      const char* src = (const char*)Wob + ((long)(o0 + col) << 11) + kb +
                        (off ^ ((col & 7) << 4));
      gload16(src, (char*)Bs + (i * 256 + wid * 64) * 16);
    }
    __syncthreads();
#pragma unroll
    for (int ks = 0; ks < 2; ++ks) {
      const int kbyte = ks * 64 + hi * 16;
      const int ra = wr * 32 + l15;
      short8 a0 = lds8((const char*)As + ra * 128 + (kbyte ^ ((ra & 7) << 4)));
      const int rb = ra + 16;
      short8 a1 = lds8((const char*)As + rb * 128 + (kbyte ^ ((rb & 7) << 4)));
#pragma unroll
      for (int f = 0; f < 4; ++f) {
        const int colx = wc * 64 + f * 16 + l15;
        short8 b = lds8((const char*)Bs + colx * 128 + (kbyte ^ ((colx & 7) << 4)));
        acc[0][f] = __builtin_amdgcn_mfma_f32_16x16x32_bf16(a0, b, acc[0][f], 0, 0, 0);
        acc[1][f] = __builtin_amdgcn_mfma_f32_16x16x32_bf16(a1, b, acc[1][f], 0, 0, 0);
      }
    }
    __syncthreads();
  }

#pragma unroll
  for (int f = 0; f < 4; ++f) {
    const int o = o0 + wc * 64 + f * 16 + l15;
    const float bb = b_out[o];
#pragma unroll
    for (int a2 = 0; a2 < 2; ++a2)
#pragma unroll
      for (int r = 0; r < 4; ++r) {
        const int row = m0 + wr * 32 + a2 * 16 + hi * 4 + r;
        out[((long)row * kT + t) * kO + o] = acc[a2][f][r] + bb;
      }
  }
}

// ---------------- launcher ----------------
extern "C" void kernel_launch(void* const* d_in, const int* in_sizes, int n_in,
                              void* d_out, int out_size, void* d_ws, size_t ws_size,
                              hipStream_t stream) {
  const float* enc  = (const float*)d_in[0];
  const float* Wih  = (const float*)d_in[2];
  const float* Whh  = (const float*)d_in[3];
  const float* bih  = (const float*)d_in[4];
  const float* bhh  = (const float*)d_in[5];
  const float* Wout = (const float*)d_in[6];
  const float* bout = (const float*)d_in[7];
  float* out = (float*)d_out;
  char*  ws  = (char*)d_ws;

  size_t off = 0;
  auto take = [&](size_t bytes) {
    size_t o = off; off += (bytes + 255) & ~(size_t)255; return o;
  };
  u16*   Wt0   = (u16*)(ws + take((size_t)kG * kH * 2));   // 8 MB
  u16*   Wt1   = (u16*)(ws + take((size_t)kG * kH * 2));   // 8 MB
  u16*   Wob   = (u16*)(ws + take((size_t)kO * kH * 2));   // 0.5 MB
  float* bias0 = (float*)(ws + take((size_t)kG * 4));
  float* bias1 = (float*)(ws + take((size_t)kG * 4));
  float* cst   = (float*)(ws + take((size_t)kB * kH * 4)); // 2 MB
  u32*   bar   = (u32*)(ws + take(512 * 4));               // 2 KB
  const long HS = (long)kB * kH;
  u16* Hbuf = (u16*)(ws + off);
  const size_t havail = ws_size > off ? ws_size - off : 0;
  const bool fullhist = havail >= (size_t)(kT + 1) * HS * 2;
  const int nsl = fullhist ? (kT + 1) : 2;

  k_init<<<dim3(kB * kH / 256), dim3(256), 0, stream>>>(enc, cst, Hbuf);
  k_zbar<<<dim3(1), dim3(512), 0, stream>>>(bar);
  k_bias<<<dim3(kG / 256), dim3(256), 0, stream>>>(bih, bhh, Wih, bout, bias0, bias1);
  k_w0<<<dim3(kG), dim3(256), 0, stream>>>(Whh, Wt0);
  k_wo<<<dim3(kO * kH / 1024), dim3(256), 0, stream>>>(Wout, Wob);
  k_w1<<<dim3(256), dim3(256), 0, stream>>>(Wih, Wout, Whh, Wt1);

  if (fullhist) {
    k_step<<<dim3(kH / 32, kB / 64), dim3(256), 0, stream>>>(
        Hbuf, Hbuf + HS, cst, Wt0, bias0);
    k_persist<<<dim3(256), dim3(512), 0, stream>>>(Wt1, bias1, cst, Hbuf, bar);
    k_pred<<<dim3(kO / 128, kB / 64, kT), dim3(256), 0, stream>>>(
        Hbuf, HS, nsl, Wob, bout, out, 0);
  } else {
    for (int t = 0; t < kT; ++t) {
      const u16* Xp = Hbuf + (long)(t % nsl) * HS;
      u16*       Hn = Hbuf + (long)((t + 1) % nsl) * HS;
      k_step<<<dim3(kH / 32, kB / 64), dim3(256), 0, stream>>>(
          Xp, Hn, cst, t == 0 ? Wt0 : Wt1, t == 0 ? bias0 : bias1);
      k_pred<<<dim3(kO / 128, kB / 64, 1), dim3(256), 0, stream>>>(
          Hbuf, HS, nsl, Wob, bout, out, t);
    }
  }
}

// Round 7
// 1500.039 us; speedup vs baseline: 2.1264x; 1.3261x over previous
//
#include <hip/hip_runtime.h>
#include <hip/hip_bf16.h>

using short8  = __attribute__((ext_vector_type(8))) short;
using floatx4 = __attribute__((ext_vector_type(4))) float;
typedef unsigned short u16;
typedef unsigned int   u32;

#define DEVINL static __device__ __forceinline__

constexpr int kB = 512;    // batch
constexpr int kH = 1024;   // hidden
constexpr int kO = 256;    // output dim
constexpr int kT = 128;    // timesteps
constexpr int kG = 4096;   // 4*H gate columns

DEVINL u16 f2bf(float x) {
  union { float f; unsigned u; } v; v.f = x;
  unsigned r = v.u + 0x7fffu + ((v.u >> 16) & 1u);   // RNE
  return (u16)(r >> 16);
}
DEVINL float sigm(float x)  { return 1.0f / (1.0f + __expf(-x)); }
DEVINL float tanhx(float x) { return 1.0f - 2.0f / (__expf(2.0f * x) + 1.0f); }

DEVINL void gload16(const void* src, void* ldsbase) {
  __builtin_amdgcn_global_load_lds((__attribute__((address_space(1))) void*)(char*)src,
                                   (__attribute__((address_space(3))) void*)ldsbase,
                                   16, 0, 0);
}
DEVINL short8 lds8(const void* p) { return *(const short8*)p; }

// ---------------- prep kernels ----------------

__global__ void k_init(const float* __restrict__ enc, float* __restrict__ c,
                       u16* __restrict__ h0) {
  int i = blockIdx.x * 256 + threadIdx.x;
  c[i]  = 0.0f;
  h0[i] = f2bf(enc[i]);
}

__global__ void k_zbar(u32* __restrict__ bar) {
  bar[threadIdx.x] = 0u;   // 512 counters (128 steps x 4 groups)
}

// bias0 = b_ih + b_hh ; bias1 = bias0 + W_ih @ b_out
__global__ void k_bias(const float* __restrict__ bih, const float* __restrict__ bhh,
                       const float* __restrict__ Wih, const float* __restrict__ bout,
                       float* __restrict__ bias0, float* __restrict__ bias1) {
  int n = blockIdx.x * 256 + threadIdx.x;        // 0..4095
  float b0 = bih[n] + bhh[n];
  const float* row = Wih + (long)n * 256;
  float s = 0.f;
  for (int j = 0; j < 256; ++j) s += row[j] * bout[j];
  bias0[n] = b0;
  bias1[n] = b0 + s;
}

// Wt0[r(n,g)][k] = bf16(W_hh[g*1024+n][k]);  r(n,g) = (n>>4)*64 + g*16 + (n&15)
__global__ void k_w0(const float* __restrict__ Whh, u16* __restrict__ Wt0) {
  const int r = blockIdx.x;                       // 4096 rows
  const int k = threadIdx.x * 4;
  const int n = ((r >> 6) << 4) | (r & 15);
  const int g = (r >> 4) & 3;
  const float4 v = *(const float4*)(Whh + (long)(g * 1024 + n) * 1024 + k);
  ushort4 o; o.x = f2bf(v.x); o.y = f2bf(v.y); o.z = f2bf(v.z); o.w = f2bf(v.w);
  *(ushort4*)(Wt0 + (long)r * 1024 + k) = o;
}

// Wob = bf16(W_out)
__global__ void k_wo(const float* __restrict__ Wout, u16* __restrict__ Wob) {
  const long i = ((long)blockIdx.x * 256 + threadIdx.x) * 4;
  const float4 v = *(const float4*)(Wout + i);
  ushort4 o; o.x = f2bf(v.x); o.y = f2bf(v.y); o.z = f2bf(v.z); o.w = f2bf(v.w);
  *(ushort4*)(Wob + i) = o;
}

// Wt1[r(n,g)][k] = bf16( W_hh[g*1024+n][k] + sum_j W_out[j][k]*W_ih[g*1024+n][j] )
__global__ __launch_bounds__(256) void k_w1(
    const float* __restrict__ Wih, const float* __restrict__ Wout,
    const float* __restrict__ Whh, u16* __restrict__ Wt1) {
  __shared__ float sW[16][256];
  const int g = blockIdx.x & 3, n16 = blockIdx.x >> 2;
  const int tid = threadIdx.x;
#pragma unroll
  for (int nl = 0; nl < 16; ++nl)
    sW[nl][tid] = Wih[(long)(g * 1024 + n16 * 16 + nl) * 256 + tid];
  __syncthreads();
  const int k4 = tid * 4;
  float acc[16][4];
#pragma unroll
  for (int nl = 0; nl < 16; ++nl)
#pragma unroll
    for (int q = 0; q < 4; ++q) acc[nl][q] = 0.f;
  for (int j = 0; j < 256; ++j) {
    const float4 wo = *(const float4*)(Wout + (long)j * 1024 + k4);
#pragma unroll
    for (int nl = 0; nl < 16; ++nl) {
      const float w = sW[nl][j];
      acc[nl][0] += w * wo.x; acc[nl][1] += w * wo.y;
      acc[nl][2] += w * wo.z; acc[nl][3] += w * wo.w;
    }
  }
#pragma unroll
  for (int nl = 0; nl < 16; ++nl) {
    const int n = n16 * 16 + nl;
    const int rout = n16 * 64 + g * 16 + nl;
    const float* hh = Whh + (long)(g * 1024 + n) * 1024 + k4;
    ushort4 o;
    o.x = f2bf(hh[0] + acc[nl][0]); o.y = f2bf(hh[1] + acc[nl][1]);
    o.z = f2bf(hh[2] + acc[nl][2]); o.w = f2bf(hh[3] + acc[nl][3]);
    *(ushort4*)(Wt1 + (long)rout * 1024 + k4) = o;
  }
}

// ---------------- step 0 (old-style, Wt0/bias0) ----------------
__global__ __launch_bounds__(256) void k_step(
    const u16* __restrict__ Xprev, u16* __restrict__ Hnext,
    float* __restrict__ c, const u16* __restrict__ Wt,
    const float* __restrict__ bias) {
  __shared__ u16 As[64 * 64];
  __shared__ u16 Bs[128 * 64];

  const int tid  = threadIdx.x;
  const int lane = tid & 63;
  const int wid  = tid >> 6;
  const int wr   = wid >> 1;
  const int wc   = wid & 1;
  const int n0   = blockIdx.x * 32;
  const int m0   = blockIdx.y * 64;
  const long wrow0 = (long)n0 * 4;
  const int hi  = lane >> 4;
  const int l15 = lane & 15;

  floatx4 acc[2][4];
#pragma unroll
  for (int a2 = 0; a2 < 2; ++a2)
#pragma unroll
    for (int f = 0; f < 4; ++f)
#pragma unroll
      for (int r = 0; r < 4; ++r) acc[a2][f][r] = 0.0f;

  for (int kt = 0; kt < 16; ++kt) {
    const int kb = kt * 128;
#pragma unroll
    for (int i = 0; i < 2; ++i) {
      const int u = i * 256 + tid;
      const int row = u >> 3;
      const int off = (u & 7) * 16;
      const char* src = (const char*)Xprev + ((long)(m0 + row) << 11) + kb +
                        (off ^ ((row & 7) << 4));
      gload16(src, (char*)As + (i * 256 + wid * 64) * 16);
    }
#pragma unroll
    for (int i = 0; i < 4; ++i) {
      const int u = i * 256 + tid;
      const int col = u >> 3;
      const int off = (u & 7) * 16;
      const char* src = (const char*)Wt + ((wrow0 + col) << 11) + kb +
                        (off ^ ((col & 7) << 4));
      gload16(src, (char*)Bs + (i * 256 + wid * 64) * 16);
    }
    __syncthreads();
#pragma unroll
    for (int ks = 0; ks < 2; ++ks) {
      const int kbyte = ks * 64 + hi * 16;
      const int ra = wr * 32 + l15;
      short8 a0 = lds8((const char*)As + ra * 128 + (kbyte ^ ((ra & 7) << 4)));
      const int rb = ra + 16;
      short8 a1 = lds8((const char*)As + rb * 128 + (kbyte ^ ((rb & 7) << 4)));
#pragma unroll
      for (int f = 0; f < 4; ++f) {
        const int colx = wc * 64 + f * 16 + l15;
        short8 b = lds8((const char*)Bs + colx * 128 + (kbyte ^ ((colx & 7) << 4)));
        acc[0][f] = __builtin_amdgcn_mfma_f32_16x16x32_bf16(a0, b, acc[0][f], 0, 0, 0);
        acc[1][f] = __builtin_amdgcn_mfma_f32_16x16x32_bf16(a1, b, acc[1][f], 0, 0, 0);
      }
    }
    __syncthreads();
  }

  const int n_glob = n0 + wc * 16 + l15;
  const float bi = bias[n_glob];
  const float bf = bias[1024 + n_glob];
  const float bg = bias[2048 + n_glob];
  const float bo = bias[3072 + n_glob];
#pragma unroll
  for (int a2 = 0; a2 < 2; ++a2) {
#pragma unroll
    for (int r = 0; r < 4; ++r) {
      const int row = m0 + wr * 32 + a2 * 16 + hi * 4 + r;
      const long ci = (long)row * kH + n_glob;
      const float iv = sigm(acc[a2][0][r] + bi);
      const float fv = sigm(acc[a2][1][r] + bf);
      const float gv = tanhx(acc[a2][2][r] + bg);
      const float ov = sigm(acc[a2][3][r] + bo);
      const float cn = fv * c[ci] + iv * gv;
      c[ci] = cn;
      Hnext[ci] = f2bf(ov * tanhx(cn));
    }
  }
}

// ---------------- persistent recurrence: steps 1..127 ----------------
// 256 blocks (1/CU, 128KB LDS), 8 waves. Block (bg,hg) owns batch rows
// bg*128.. and Wt1 rows hg*64.. (16 hidden x 4 gates). Weights LDS-resident
// in exact read order (conflict-free). c in registers.
// h handoff: RELAXED AGENT atomic stores (write-through to device coherence
// point) -> barrier is pure relaxed counters, NO wbl2/threadfence anywhere.
// Visibility: __syncthreads drains vmcnt(0) before tid0's arrival add; Hbuf
// slices are unique write-once/read-once addresses (no stale cached copies:
// pre-kernel dirty lines were flushed by the implicit end-of-dispatch fence).
__global__ __launch_bounds__(512, 2) void k_persist(
    const u16* __restrict__ Wt,      // Wt1 [4096][1024]
    const float* __restrict__ bias,  // bias1
    const float* __restrict__ cin,   // c after step 0
    u16* __restrict__ Hbuf,          // 129 slices of [512][1024]
    u32* __restrict__ bar) {
  __shared__ u16 Wlds[64 * 1024];    // 128 KB

  const int tid = threadIdx.x;
  const int l   = tid & 63;
  const int w   = tid >> 6;          // wave 0..7 -> rows w*16..
  const int l15 = l & 15;
  const int hi  = l >> 4;
  const int xcd  = blockIdx.x & 7;
  const int slot = blockIdx.x >> 3;            // 0..31
  const int bg   = xcd >> 1;                   // 0..3
  const int hg   = (xcd & 1) * 32 + slot;      // 0..63
  const int m0   = bg * 128;

  // stage weight slice once, in read-order layout:
  // LDS chunk u (16B) = (j*4+f)*64 + hi2*16 + c15  -> holds
  // Wt[hg*64 + f*16 + c15][bytes j*64 + hi2*16 .. +16]
  {
    const long wrow0 = (long)hg * 64;
#pragma unroll
    for (int rr = 0; rr < 16; ++rr) {
      const int u   = rr * 512 + tid;          // 0..8191
      const int j   = u >> 8;
      const int f   = (u >> 6) & 3;
      const int h2  = (u >> 4) & 3;
      const int c15 = u & 15;
      const char* src = (const char*)Wt + ((wrow0 + f * 16 + c15) << 11) +
                        (j << 6) + (h2 << 4);
      gload16(src, (char*)Wlds + (long)u * 16);
    }
  }

  const int ncol = hg * 16 + l15;              // hidden column owned
  const float bi = bias[ncol];
  const float bf_ = bias[1024 + ncol];
  const float bg_ = bias[2048 + ncol];
  const float bo = bias[3072 + ncol];
  const int row0 = m0 + w * 16 + hi * 4;
  float creg[4];
#pragma unroll
  for (int r = 0; r < 4; ++r) creg[r] = cin[(long)(row0 + r) * kH + ncol];

  __syncthreads();                             // weights staged (vmcnt drained)

  // two LDS bases so every ds_read_b128 offset fits the 16-bit immediate
  const char* wb0 = (const char*)Wlds + (l << 4);
  const char* wb1 = wb0 + 65536;
#define BFRAG(j, f) lds8((((j) < 16) ? wb0 : wb1) + ((((j) & 15) << 12) | ((f) << 10)))

  const long arow = (long)(m0 + w * 16 + l15) * 2048 + hi * 16;   // A byte off
  const long HSB  = (long)kB * kH * 2;                            // slice bytes

  for (int t = 1; t < kT; ++t) {
    const char* Asrc = (const char*)Hbuf + (long)t * HSB + arow;
    floatx4 ac0 = {0.f,0.f,0.f,0.f}, ac1 = ac0, ac2 = ac0, ac3 = ac0;

    // 3-deep rolling prefetch banks (12 loads in flight)
    short8 bk[3][4];
#pragma unroll
    for (int g = 0; g < 3; ++g)
#pragma unroll
      for (int q = 0; q < 4; ++q)
        bk[g][q] = *(const short8*)(Asrc + ((g * 4 + q) << 6));

#pragma unroll
    for (int jg = 0; jg < 8; ++jg) {
#pragma unroll
      for (int q = 0; q < 4; ++q) {
        const int j = jg * 4 + q;
        short8 av = bk[jg % 3][q];
        ac0 = __builtin_amdgcn_mfma_f32_16x16x32_bf16(av, BFRAG(j, 0), ac0, 0, 0, 0);
        ac1 = __builtin_amdgcn_mfma_f32_16x16x32_bf16(av, BFRAG(j, 1), ac1, 0, 0, 0);
        ac2 = __builtin_amdgcn_mfma_f32_16x16x32_bf16(av, BFRAG(j, 2), ac2, 0, 0, 0);
        ac3 = __builtin_amdgcn_mfma_f32_16x16x32_bf16(av, BFRAG(j, 3), ac3, 0, 0, 0);
      }
      if (jg < 5) {
#pragma unroll
        for (int q = 0; q < 4; ++q)
          bk[jg % 3][q] = *(const short8*)(Asrc + (((jg + 3) * 4 + q) << 6));
      }
    }

    // cell update + h write (relaxed agent-scope stores: device-visible, no L2 dirty)
    u16* Hn = (u16*)((char*)Hbuf + (long)(t + 1) * HSB);
#pragma unroll
    for (int r = 0; r < 4; ++r) {
      const float iv = sigm(ac0[r] + bi);
      const float fv = sigm(ac1[r] + bf_);
      const float gv = tanhx(ac2[r] + bg_);
      const float ov = sigm(ac3[r] + bo);
      const float cn = fv * creg[r] + iv * gv;
      creg[r] = cn;
      __hip_atomic_store(&Hn[(long)(row0 + r) * kH + ncol], f2bf(ov * tanhx(cn)),
                         __ATOMIC_RELAXED, __HIP_MEMORY_SCOPE_AGENT);
    }

    if (t < kT - 1) {
      __syncthreads();     // per-wave s_waitcnt vmcnt(0) before s_barrier:
                           // all h stores of this block are device-visible
      if (tid == 0) {
        u32* p = bar + (t * 4 + bg);
        __hip_atomic_fetch_add(p, 1u, __ATOMIC_RELAXED, __HIP_MEMORY_SCOPE_AGENT);
        int guard = 0;
        while (__hip_atomic_load(p, __ATOMIC_RELAXED, __HIP_MEMORY_SCOPE_AGENT) < 64u) {
          __builtin_amdgcn_s_sleep(2);
          if (++guard > (1 << 17)) break;      // fail visibly, never hang
        }
      }
      __syncthreads();
    }
  }
#undef BFRAG
}

// ---------------- prediction head ----------------
__global__ __launch_bounds__(256) void k_pred(
    const u16* __restrict__ Hbuf, long HS, int nsl,
    const u16* __restrict__ Wob, const float* __restrict__ b_out,
    float* __restrict__ out, int t0) {
  __shared__ u16 As[64 * 64];
  __shared__ u16 Bs[128 * 64];
  const int t = t0 + blockIdx.z;
  const u16* Hm = Hbuf + (long)((t + 1) % nsl) * HS;

  const int tid = threadIdx.x, lane = tid & 63, wid = tid >> 6;
  const int wr = wid >> 1, wc = wid & 1;
  const int m0 = blockIdx.y * 64;
  const int o0 = blockIdx.x * 128;
  const int hi = lane >> 4, l15 = lane & 15;

  floatx4 acc[2][4];
#pragma unroll
  for (int a2 = 0; a2 < 2; ++a2)
#pragma unroll
    for (int f = 0; f < 4; ++f)
#pragma unroll
      for (int r = 0; r < 4; ++r) acc[a2][f][r] = 0.0f;

  for (int kt = 0; kt < 16; ++kt) {
    const int kb = kt * 128;
#pragma unroll
    for (int i = 0; i < 2; ++i) {
      const int u = i * 256 + tid;
      const int row = u >> 3;
      const int off = (u & 7) * 16;
      const char* src = (const char*)Hm + ((long)(m0 + row) << 11) + kb +
                        (off ^ ((row & 7) << 4));
      gload16(src, (char*)As + (i * 256 + wid * 64) * 16);
    }
#pragma unroll
    for (int i = 0; i < 4; ++i) {
      const int u = i * 256 + tid;
      const int col = u >> 3;
      const int off = (u & 7) * 16;
      const char* src = (const char*)Wob + ((long)(o0 + col) << 11) + kb +
                        (off ^ ((col & 7) << 4));
      gload16(src, (char*)Bs + (i * 256 + wid * 64) * 16);
    }
    __syncthreads();
#pragma unroll
    for (int ks = 0; ks < 2; ++ks) {
      const int kbyte = ks * 64 + hi * 16;
      const int ra = wr * 32 + l15;
      short8 a0 = lds8((const char*)As + ra * 128 + (kbyte ^ ((ra & 7) << 4)));
      const int rb = ra + 16;
      short8 a1 = lds8((const char*)As + rb * 128 + (kbyte ^ ((rb & 7) << 4)));
#pragma unroll
      for (int f = 0; f < 4; ++f) {
        const int colx = wc * 64 + f * 16 + l15;
        short8 b = lds8((const char*)Bs + colx * 128 + (kbyte ^ ((colx & 7) << 4)));
        acc[0][f] = __builtin_amdgcn_mfma_f32_16x16x32_bf16(a0, b, acc[0][f], 0, 0, 0);
        acc[1][f] = __builtin_amdgcn_mfma_f32_16x16x32_bf16(a1, b, acc[1][f], 0, 0, 0);
      }
    }
    __syncthreads();
  }

#pragma unroll
  for (int f = 0; f < 4; ++f) {
    const int o = o0 + wc * 64 + f * 16 + l15;
    const float bb = b_out[o];
#pragma unroll
    for (int a2 = 0; a2 < 2; ++a2)
#pragma unroll
      for (int r = 0; r < 4; ++r) {
        const int row = m0 + wr * 32 + a2 * 16 + hi * 4 + r;
        out[((long)row * kT + t) * kO + o] = acc[a2][f][r] + bb;
      }
  }
}

// ---------------- launcher ----------------
extern "C" void kernel_launch(void* const* d_in, const int* in_sizes, int n_in,
                              void* d_out, int out_size, void* d_ws, size_t ws_size,
                              hipStream_t stream) {
  const float* enc  = (const float*)d_in[0];
  const float* Wih  = (const float*)d_in[2];
  const float* Whh  = (const float*)d_in[3];
  const float* bih  = (const float*)d_in[4];
  const float* bhh  = (const float*)d_in[5];
  const float* Wout = (const float*)d_in[6];
  const float* bout = (const float*)d_in[7];
  float* out = (float*)d_out;
  char*  ws  = (char*)d_ws;

  size_t off = 0;
  auto take = [&](size_t bytes) {
    size_t o = off; off += (bytes + 255) & ~(size_t)255; return o;
  };
  u16*   Wt0   = (u16*)(ws + take((size_t)kG * kH * 2));   // 8 MB
  u16*   Wt1   = (u16*)(ws + take((size_t)kG * kH * 2));   // 8 MB
  u16*   Wob   = (u16*)(ws + take((size_t)kO * kH * 2));   // 0.5 MB
  float* bias0 = (float*)(ws + take((size_t)kG * 4));
  float* bias1 = (float*)(ws + take((size_t)kG * 4));
  float* cst   = (float*)(ws + take((size_t)kB * kH * 4)); // 2 MB
  u32*   bar   = (u32*)(ws + take(512 * 4));               // 2 KB
  const long HS = (long)kB * kH;
  u16* Hbuf = (u16*)(ws + off);
  const size_t havail = ws_size > off ? ws_size - off : 0;
  const bool fullhist = havail >= (size_t)(kT + 1) * HS * 2;
  const int nsl = fullhist ? (kT + 1) : 2;

  k_init<<<dim3(kB * kH / 256), dim3(256), 0, stream>>>(enc, cst, Hbuf);
  k_zbar<<<dim3(1), dim3(512), 0, stream>>>(bar);
  k_bias<<<dim3(kG / 256), dim3(256), 0, stream>>>(bih, bhh, Wih, bout, bias0, bias1);
  k_w0<<<dim3(kG), dim3(256), 0, stream>>>(Whh, Wt0);
  k_wo<<<dim3(kO * kH / 1024), dim3(256), 0, stream>>>(Wout, Wob);
  k_w1<<<dim3(256), dim3(256), 0, stream>>>(Wih, Wout, Whh, Wt1);

  if (fullhist) {
    k_step<<<dim3(kH / 32, kB / 64), dim3(256), 0, stream>>>(
        Hbuf, Hbuf + HS, cst, Wt0, bias0);
    k_persist<<<dim3(256), dim3(512), 0, stream>>>(Wt1, bias1, cst, Hbuf, bar);
    k_pred<<<dim3(kO / 128, kB / 64, kT), dim3(256), 0, stream>>>(
        Hbuf, HS, nsl, Wob, bout, out, 0);
  } else {
    for (int t = 0; t < kT; ++t) {
      const u16* Xp = Hbuf + (long)(t % nsl) * HS;
      u16*       Hn = Hbuf + (long)((t + 1) % nsl) * HS;
      k_step<<<dim3(kH / 32, kB / 64), dim3(256), 0, stream>>>(
          Xp, Hn, cst, t == 0 ? Wt0 : Wt1, t == 0 ? bias0 : bias1);
      k_pred<<<dim3(kO / 128, kB / 64, 1), dim3(256), 0, stream>>>(
          Hbuf, HS, nsl, Wob, bout, out, t);
    }
  }
}

// Round 8
// 1456.398 us; speedup vs baseline: 2.1901x; 1.0300x over previous
//
#include <hip/hip_runtime.h>
#include <hip/hip_bf16.h>

using short8  = __attribute__((ext_vector_type(8))) short;
using floatx4 = __attribute__((ext_vector_type(4))) float;
typedef unsigned short u16;
typedef unsigned int   u32;

#define DEVINL static __device__ __forceinline__

constexpr int kB = 512;    // batch
constexpr int kH = 1024;   // hidden
constexpr int kO = 256;    // output dim
constexpr int kT = 128;    // timesteps
constexpr int kG = 4096;   // 4*H gate columns

DEVINL u16 f2bf(float x) {
  union { float f; unsigned u; } v; v.f = x;
  unsigned r = v.u + 0x7fffu + ((v.u >> 16) & 1u);   // RNE
  return (u16)(r >> 16);
}
DEVINL float sigm(float x)  { return 1.0f / (1.0f + __expf(-x)); }
DEVINL float tanhx(float x) { return 1.0f - 2.0f / (__expf(2.0f * x) + 1.0f); }

DEVINL void gload16(const void* src, void* ldsbase) {
  __builtin_amdgcn_global_load_lds((__attribute__((address_space(1))) void*)(char*)src,
                                   (__attribute__((address_space(3))) void*)ldsbase,
                                   16, 0, 0);
}
DEVINL short8 lds8(const void* p) { return *(const short8*)p; }

// ---------------- prep kernels ----------------

__global__ void k_init(const float* __restrict__ enc, float* __restrict__ c,
                       u16* __restrict__ h0) {
  int i = blockIdx.x * 256 + threadIdx.x;
  c[i]  = 0.0f;
  h0[i] = f2bf(enc[i]);
}

// zero the 256 per-block arrival slots (128B stride -> 8192 u32 = 32 KB)
__global__ void k_zbar(u32* __restrict__ bar) {
  bar[blockIdx.x * 256 + threadIdx.x] = 0u;
}

// bias0 = b_ih + b_hh ; bias1 = bias0 + W_ih @ b_out
__global__ void k_bias(const float* __restrict__ bih, const float* __restrict__ bhh,
                       const float* __restrict__ Wih, const float* __restrict__ bout,
                       float* __restrict__ bias0, float* __restrict__ bias1) {
  int n = blockIdx.x * 256 + threadIdx.x;        // 0..4095
  float b0 = bih[n] + bhh[n];
  const float* row = Wih + (long)n * 256;
  float s = 0.f;
  for (int j = 0; j < 256; ++j) s += row[j] * bout[j];
  bias0[n] = b0;
  bias1[n] = b0 + s;
}

// Wt0[r(n,g)][k] = bf16(W_hh[g*1024+n][k]);  r(n,g) = (n>>4)*64 + g*16 + (n&15)
__global__ void k_w0(const float* __restrict__ Whh, u16* __restrict__ Wt0) {
  const int r = blockIdx.x;                       // 4096 rows
  const int k = threadIdx.x * 4;
  const int n = ((r >> 6) << 4) | (r & 15);
  const int g = (r >> 4) & 3;
  const float4 v = *(const float4*)(Whh + (long)(g * 1024 + n) * 1024 + k);
  ushort4 o; o.x = f2bf(v.x); o.y = f2bf(v.y); o.z = f2bf(v.z); o.w = f2bf(v.w);
  *(ushort4*)(Wt0 + (long)r * 1024 + k) = o;
}

// Wob = bf16(W_out)
__global__ void k_wo(const float* __restrict__ Wout, u16* __restrict__ Wob) {
  const long i = ((long)blockIdx.x * 256 + threadIdx.x) * 4;
  const float4 v = *(const float4*)(Wout + i);
  ushort4 o; o.x = f2bf(v.x); o.y = f2bf(v.y); o.z = f2bf(v.z); o.w = f2bf(v.w);
  *(ushort4*)(Wob + i) = o;
}

// Wt1[r(n,g)][k] = bf16( W_hh[g*1024+n][k] + sum_j W_out[j][k]*W_ih[g*1024+n][j] )
__global__ __launch_bounds__(256) void k_w1(
    const float* __restrict__ Wih, const float* __restrict__ Wout,
    const float* __restrict__ Whh, u16* __restrict__ Wt1) {
  __shared__ float sW[16][256];
  const int g = blockIdx.x & 3, n16 = blockIdx.x >> 2;
  const int tid = threadIdx.x;
#pragma unroll
  for (int nl = 0; nl < 16; ++nl)
    sW[nl][tid] = Wih[(long)(g * 1024 + n16 * 16 + nl) * 256 + tid];
  __syncthreads();
  const int k4 = tid * 4;
  float acc[16][4];
#pragma unroll
  for (int nl = 0; nl < 16; ++nl)
#pragma unroll
    for (int q = 0; q < 4; ++q) acc[nl][q] = 0.f;
  for (int j = 0; j < 256; ++j) {
    const float4 wo = *(const float4*)(Wout + (long)j * 1024 + k4);
#pragma unroll
    for (int nl = 0; nl < 16; ++nl) {
      const float w = sW[nl][j];
      acc[nl][0] += w * wo.x; acc[nl][1] += w * wo.y;
      acc[nl][2] += w * wo.z; acc[nl][3] += w * wo.w;
    }
  }
#pragma unroll
  for (int nl = 0; nl < 16; ++nl) {
    const int n = n16 * 16 + nl;
    const int rout = n16 * 64 + g * 16 + nl;
    const float* hh = Whh + (long)(g * 1024 + n) * 1024 + k4;
    ushort4 o;
    o.x = f2bf(hh[0] + acc[nl][0]); o.y = f2bf(hh[1] + acc[nl][1]);
    o.z = f2bf(hh[2] + acc[nl][2]); o.w = f2bf(hh[3] + acc[nl][3]);
    *(ushort4*)(Wt1 + (long)rout * 1024 + k4) = o;
  }
}

// ---------------- step 0 (old-style, Wt0/bias0) ----------------
__global__ __launch_bounds__(256) void k_step(
    const u16* __restrict__ Xprev, u16* __restrict__ Hnext,
    float* __restrict__ c, const u16* __restrict__ Wt,
    const float* __restrict__ bias) {
  __shared__ u16 As[64 * 64];
  __shared__ u16 Bs[128 * 64];

  const int tid  = threadIdx.x;
  const int lane = tid & 63;
  const int wid  = tid >> 6;
  const int wr   = wid >> 1;
  const int wc   = wid & 1;
  const int n0   = blockIdx.x * 32;
  const int m0   = blockIdx.y * 64;
  const long wrow0 = (long)n0 * 4;
  const int hi  = lane >> 4;
  const int l15 = lane & 15;

  floatx4 acc[2][4];
#pragma unroll
  for (int a2 = 0; a2 < 2; ++a2)
#pragma unroll
    for (int f = 0; f < 4; ++f)
#pragma unroll
      for (int r = 0; r < 4; ++r) acc[a2][f][r] = 0.0f;

  for (int kt = 0; kt < 16; ++kt) {
    const int kb = kt * 128;
#pragma unroll
    for (int i = 0; i < 2; ++i) {
      const int u = i * 256 + tid;
      const int row = u >> 3;
      const int off = (u & 7) * 16;
      const char* src = (const char*)Xprev + ((long)(m0 + row) << 11) + kb +
                        (off ^ ((row & 7) << 4));
      gload16(src, (char*)As + (i * 256 + wid * 64) * 16);
    }
#pragma unroll
    for (int i = 0; i < 4; ++i) {
      const int u = i * 256 + tid;
      const int col = u >> 3;
      const int off = (u & 7) * 16;
      const char* src = (const char*)Wt + ((wrow0 + col) << 11) + kb +
                        (off ^ ((col & 7) << 4));
      gload16(src, (char*)Bs + (i * 256 + wid * 64) * 16);
    }
    __syncthreads();
#pragma unroll
    for (int ks = 0; ks < 2; ++ks) {
      const int kbyte = ks * 64 + hi * 16;
      const int ra = wr * 32 + l15;
      short8 a0 = lds8((const char*)As + ra * 128 + (kbyte ^ ((ra & 7) << 4)));
      const int rb = ra + 16;
      short8 a1 = lds8((const char*)As + rb * 128 + (kbyte ^ ((rb & 7) << 4)));
#pragma unroll
      for (int f = 0; f < 4; ++f) {
        const int colx = wc * 64 + f * 16 + l15;
        short8 b = lds8((const char*)Bs + colx * 128 + (kbyte ^ ((colx & 7) << 4)));
        acc[0][f] = __builtin_amdgcn_mfma_f32_16x16x32_bf16(a0, b, acc[0][f], 0, 0, 0);
        acc[1][f] = __builtin_amdgcn_mfma_f32_16x16x32_bf16(a1, b, acc[1][f], 0, 0, 0);
      }
    }
    __syncthreads();
  }

  const int n_glob = n0 + wc * 16 + l15;
  const float bi = bias[n_glob];
  const float bf = bias[1024 + n_glob];
  const float bg = bias[2048 + n_glob];
  const float bo = bias[3072 + n_glob];
#pragma unroll
  for (int a2 = 0; a2 < 2; ++a2) {
#pragma unroll
    for (int r = 0; r < 4; ++r) {
      const int row = m0 + wr * 32 + a2 * 16 + hi * 4 + r;
      const long ci = (long)row * kH + n_glob;
      const float iv = sigm(acc[a2][0][r] + bi);
      const float fv = sigm(acc[a2][1][r] + bf);
      const float gv = tanhx(acc[a2][2][r] + bg);
      const float ov = sigm(acc[a2][3][r] + bo);
      const float cn = fv * c[ci] + iv * gv;
      c[ci] = cn;
      Hnext[ci] = f2bf(ov * tanhx(cn));
    }
  }
}

// ---------------- persistent recurrence: steps 1..127 ----------------
// 256 blocks (1/CU, 128KB LDS), 8 waves. Block (bg,hg) owns batch rows
// bg*128.. and Wt1 rows hg*64.. (16 hidden x 4 gates). Weights LDS-resident
// in exact read order (conflict-free). c in registers.
// h handoff: RELAXED AGENT atomic stores (write-through). Barrier: per-block
// arrival SLOT (own 128B line, plain relaxed store -> no RMW serialization);
// wave 0's 64 lanes each poll one producer block's slot (parallel loads to
// 64 distinct lines), divergent while-loop releases when all arrived.
__global__ __launch_bounds__(512, 2) void k_persist(
    const u16* __restrict__ Wt,      // Wt1 [4096][1024]
    const float* __restrict__ bias,  // bias1
    const float* __restrict__ cin,   // c after step 0
    u16* __restrict__ Hbuf,          // 129 slices of [512][1024]
    u32* __restrict__ bar) {         // 256 slots, 128B stride
  __shared__ u16 Wlds[64 * 1024];    // 128 KB

  const int tid = threadIdx.x;
  const int l   = tid & 63;
  const int w   = tid >> 6;          // wave 0..7 -> rows w*16..
  const int l15 = l & 15;
  const int hi  = l >> 4;
  const int xcd  = blockIdx.x & 7;
  const int slot = blockIdx.x >> 3;            // 0..31
  const int bg   = xcd >> 1;                   // 0..3
  const int hg   = (xcd & 1) * 32 + slot;      // 0..63
  const int m0   = bg * 128;
  const int myblk = blockIdx.x;
  // producer block polled by this lane (only wave 0 uses it):
  // bg group = xcds {2bg, 2bg+1} x slots 0..31 ; blk = slot*8 + xcd
  const int pblk = ((l & 31) * 8) + (bg * 2) + (l >> 5);

  // stage weight slice once, in read-order layout:
  // LDS chunk u (16B) = (j*4+f)*64 + hi2*16 + c15  -> holds
  // Wt[hg*64 + f*16 + c15][bytes j*64 + hi2*16 .. +16]
  {
    const long wrow0 = (long)hg * 64;
#pragma unroll
    for (int rr = 0; rr < 16; ++rr) {
      const int u   = rr * 512 + tid;          // 0..8191
      const int j   = u >> 8;
      const int f   = (u >> 6) & 3;
      const int h2  = (u >> 4) & 3;
      const int c15 = u & 15;
      const char* src = (const char*)Wt + ((wrow0 + f * 16 + c15) << 11) +
                        (j << 6) + (h2 << 4);
      gload16(src, (char*)Wlds + (long)u * 16);
    }
  }

  const int ncol = hg * 16 + l15;              // hidden column owned
  const float bi = bias[ncol];
  const float bf_ = bias[1024 + ncol];
  const float bg_ = bias[2048 + ncol];
  const float bo = bias[3072 + ncol];
  const int row0 = m0 + w * 16 + hi * 4;
  float creg[4];
#pragma unroll
  for (int r = 0; r < 4; ++r) creg[r] = cin[(long)(row0 + r) * kH + ncol];

  __syncthreads();                             // weights staged (vmcnt drained)

  // two LDS bases so every ds_read_b128 offset fits the 16-bit immediate
  const char* wb0 = (const char*)Wlds + (l << 4);
  const char* wb1 = wb0 + 65536;
#define BFRAG(j, f) lds8((((j) < 16) ? wb0 : wb1) + ((((j) & 15) << 12) | ((f) << 10)))

  const long arow = (long)(m0 + w * 16 + l15) * 2048 + hi * 16;   // A byte off
  const long HSB  = (long)kB * kH * 2;                            // slice bytes

  for (int t = 1; t < kT; ++t) {
    const char* Asrc = (const char*)Hbuf + (long)t * HSB + arow;
    floatx4 ac0 = {0.f,0.f,0.f,0.f}, ac1 = ac0, ac2 = ac0, ac3 = ac0;

    // 3-deep rolling prefetch banks (12 loads in flight)
    short8 bk[3][4];
#pragma unroll
    for (int g = 0; g < 3; ++g)
#pragma unroll
      for (int q = 0; q < 4; ++q)
        bk[g][q] = *(const short8*)(Asrc + ((g * 4 + q) << 6));

#pragma unroll
    for (int jg = 0; jg < 8; ++jg) {
#pragma unroll
      for (int q = 0; q < 4; ++q) {
        const int j = jg * 4 + q;
        short8 av = bk[jg % 3][q];
        ac0 = __builtin_amdgcn_mfma_f32_16x16x32_bf16(av, BFRAG(j, 0), ac0, 0, 0, 0);
        ac1 = __builtin_amdgcn_mfma_f32_16x16x32_bf16(av, BFRAG(j, 1), ac1, 0, 0, 0);
        ac2 = __builtin_amdgcn_mfma_f32_16x16x32_bf16(av, BFRAG(j, 2), ac2, 0, 0, 0);
        ac3 = __builtin_amdgcn_mfma_f32_16x16x32_bf16(av, BFRAG(j, 3), ac3, 0, 0, 0);
      }
      if (jg < 5) {
#pragma unroll
        for (int q = 0; q < 4; ++q)
          bk[jg % 3][q] = *(const short8*)(Asrc + (((jg + 3) * 4 + q) << 6));
      }
    }

    // cell update + h write (relaxed agent-scope stores: device-visible)
    u16* Hn = (u16*)((char*)Hbuf + (long)(t + 1) * HSB);
#pragma unroll
    for (int r = 0; r < 4; ++r) {
      const float iv = sigm(ac0[r] + bi);
      const float fv = sigm(ac1[r] + bf_);
      const float gv = tanhx(ac2[r] + bg_);
      const float ov = sigm(ac3[r] + bo);
      const float cn = fv * creg[r] + iv * gv;
      creg[r] = cn;
      __hip_atomic_store(&Hn[(long)(row0 + r) * kH + ncol], f2bf(ov * tanhx(cn)),
                         __ATOMIC_RELAXED, __HIP_MEMORY_SCOPE_AGENT);
    }

    if (t < kT - 1) {
      __syncthreads();     // per-wave s_waitcnt vmcnt(0) before s_barrier:
                           // all h stores of this block are device-visible
      if (tid == 0)        // own line: plain relaxed store, no RMW
        __hip_atomic_store(bar + myblk * 32, (u32)t,
                           __ATOMIC_RELAXED, __HIP_MEMORY_SCOPE_AGENT);
      if (tid < 64) {      // wave 0: lane l polls producer pblk's slot
        int guard = 0;
        while (__hip_atomic_load(bar + pblk * 32, __ATOMIC_RELAXED,
                                 __HIP_MEMORY_SCOPE_AGENT) < (u32)t) {
          __builtin_amdgcn_s_sleep(1);
          if (++guard > (1 << 20)) break;      // fail visibly, never hang
        }
      }
      __syncthreads();
    }
  }
#undef BFRAG
}

// ---------------- prediction head ----------------
__global__ __launch_bounds__(256) void k_pred(
    const u16* __restrict__ Hbuf, long HS, int nsl,
    const u16* __restrict__ Wob, const float* __restrict__ b_out,
    float* __restrict__ out, int t0) {
  __shared__ u16 As[64 * 64];
  __shared__ u16 Bs[128 * 64];
  const int t = t0 + blockIdx.z;
  const u16* Hm = Hbuf + (long)((t + 1) % nsl) * HS;

  const int tid = threadIdx.x, lane = tid & 63, wid = tid >> 6;
  const int wr = wid >> 1, wc = wid & 1;
  const int m0 = blockIdx.y * 64;
  const int o0 = blockIdx.x * 128;
  const int hi = lane >> 4, l15 = lane & 15;

  floatx4 acc[2][4];
#pragma unroll
  for (int a2 = 0; a2 < 2; ++a2)
#pragma unroll
    for (int f = 0; f < 4; ++f)
#pragma unroll
      for (int r = 0; r < 4; ++r) acc[a2][f][r] = 0.0f;

  for (int kt = 0; kt < 16; ++kt) {
    const int kb = kt * 128;
#pragma unroll
    for (int i = 0; i < 2; ++i) {
      const int u = i * 256 + tid;
      const int row = u >> 3;
      const int off = (u & 7) * 16;
      const char* src = (const char*)Hm + ((long)(m0 + row) << 11) + kb +
                        (off ^ ((row & 7) << 4));
      gload16(src, (char*)As + (i * 256 + wid * 64) * 16);
    }
#pragma unroll
    for (int i = 0; i < 4; ++i) {
      const int u = i * 256 + tid;
      const int col = u >> 3;
      const int off = (u & 7) * 16;
      const char* src = (const char*)Wob + ((long)(o0 + col) << 11) + kb +
                        (off ^ ((col & 7) << 4));
      gload16(src, (char*)Bs + (i * 256 + wid * 64) * 16);
    }
    __syncthreads();
#pragma unroll
    for (int ks = 0; ks < 2; ++ks) {
      const int kbyte = ks * 64 + hi * 16;
      const int ra = wr * 32 + l15;
      short8 a0 = lds8((const char*)As + ra * 128 + (kbyte ^ ((ra & 7) << 4)));
      const int rb = ra + 16;
      short8 a1 = lds8((const char*)As + rb * 128 + (kbyte ^ ((rb & 7) << 4)));
#pragma unroll
      for (int f = 0; f < 4; ++f) {
        const int colx = wc * 64 + f * 16 + l15;
        short8 b = lds8((const char*)Bs + colx * 128 + (kbyte ^ ((colx & 7) << 4)));
        acc[0][f] = __builtin_amdgcn_mfma_f32_16x16x32_bf16(a0, b, acc[0][f], 0, 0, 0);
        acc[1][f] = __builtin_amdgcn_mfma_f32_16x16x32_bf16(a1, b, acc[1][f], 0, 0, 0);
      }
    }
    __syncthreads();
  }

#pragma unroll
  for (int f = 0; f < 4; ++f) {
    const int o = o0 + wc * 64 + f * 16 + l15;
    const float bb = b_out[o];
#pragma unroll
    for (int a2 = 0; a2 < 2; ++a2)
#pragma unroll
      for (int r = 0; r < 4; ++r) {
        const int row = m0 + wr * 32 + a2 * 16 + hi * 4 + r;
        out[((long)row * kT + t) * kO + o] = acc[a2][f][r] + bb;
      }
  }
}

// ---------------- launcher ----------------
extern "C" void kernel_launch(void* const* d_in, const int* in_sizes, int n_in,
                              void* d_out, int out_size, void* d_ws, size_t ws_size,
                              hipStream_t stream) {
  const float* enc  = (const float*)d_in[0];
  const float* Wih  = (const float*)d_in[2];
  const float* Whh  = (const float*)d_in[3];
  const float* bih  = (const float*)d_in[4];
  const float* bhh  = (const float*)d_in[5];
  const float* Wout = (const float*)d_in[6];
  const float* bout = (const float*)d_in[7];
  float* out = (float*)d_out;
  char*  ws  = (char*)d_ws;

  size_t off = 0;
  auto take = [&](size_t bytes) {
    size_t o = off; off += (bytes + 255) & ~(size_t)255; return o;
  };
  u16*   Wt0   = (u16*)(ws + take((size_t)kG * kH * 2));   // 8 MB
  u16*   Wt1   = (u16*)(ws + take((size_t)kG * kH * 2));   // 8 MB
  u16*   Wob   = (u16*)(ws + take((size_t)kO * kH * 2));   // 0.5 MB
  float* bias0 = (float*)(ws + take((size_t)kG * 4));
  float* bias1 = (float*)(ws + take((size_t)kG * 4));
  float* cst   = (float*)(ws + take((size_t)kB * kH * 4)); // 2 MB
  u32*   bar   = (u32*)(ws + take(256 * 128));             // 32 KB arrival slots
  const long HS = (long)kB * kH;
  u16* Hbuf = (u16*)(ws + off);
  const size_t havail = ws_size > off ? ws_size - off : 0;
  const bool fullhist = havail >= (size_t)(kT + 1) * HS * 2;
  const int nsl = fullhist ? (kT + 1) : 2;

  k_init<<<dim3(kB * kH / 256), dim3(256), 0, stream>>>(enc, cst, Hbuf);
  k_zbar<<<dim3(32), dim3(256), 0, stream>>>(bar);
  k_bias<<<dim3(kG / 256), dim3(256), 0, stream>>>(bih, bhh, Wih, bout, bias0, bias1);
  k_w0<<<dim3(kG), dim3(256), 0, stream>>>(Whh, Wt0);
  k_wo<<<dim3(kO * kH / 1024), dim3(256), 0, stream>>>(Wout, Wob);
  k_w1<<<dim3(256), dim3(256), 0, stream>>>(Wih, Wout, Whh, Wt1);

  if (fullhist) {
    k_step<<<dim3(kH / 32, kB / 64), dim3(256), 0, stream>>>(
        Hbuf, Hbuf + HS, cst, Wt0, bias0);
    k_persist<<<dim3(256), dim3(512), 0, stream>>>(Wt1, bias1, cst, Hbuf, bar);
    k_pred<<<dim3(kO / 128, kB / 64, kT), dim3(256), 0, stream>>>(
        Hbuf, HS, nsl, Wob, bout, out, 0);
  } else {
    for (int t = 0; t < kT; ++t) {
      const u16* Xp = Hbuf + (long)(t % nsl) * HS;
      u16*       Hn = Hbuf + (long)((t + 1) % nsl) * HS;
      k_step<<<dim3(kH / 32, kB / 64), dim3(256), 0, stream>>>(
          Xp, Hn, cst, t == 0 ? Wt0 : Wt1, t == 0 ? bias0 : bias1);
      k_pred<<<dim3(kO / 128, kB / 64, 1), dim3(256), 0, stream>>>(
          Hbuf, HS, nsl, Wob, bout, out, t);
    }
  }
}